// Round 6
// baseline (125.833 us; speedup 1.0000x reference)
//
#include <hip/hip_runtime.h>
#include <math.h>

namespace {

constexpr int B  = 8;
constexpr int N  = 6;
constexpr int D  = 41;
constexpr int FH = 8;    // 128/16
constexpr int FW = 22;   // 352/16
constexpr int C  = 64;
constexpr int NPTS = B * N * D * FH * FW;   // 346368 = 1353 * 256
constexpr int NX0 = 200, NX1 = 200, NX2 = 1;
constexpr int NVOX = NX0 * NX1;             // 40000 voxels per batch (gz==0)
constexpr int MAT_STRIDE = 24;
constexpr int VTILES = NVOX / 64;           // 625 tiles per batch
constexpr int NTILES = B * VTILES;          // 5000
constexpr int CAP    = 4096;                // bin capacity per tile (ints)

__device__ inline void inv3x3(const float a[9], float r[9]) {
  float c00 = a[4] * a[8] - a[5] * a[7];
  float c01 = a[5] * a[6] - a[3] * a[8];
  float c02 = a[3] * a[7] - a[4] * a[6];
  float det = a[0] * c00 + a[1] * c01 + a[2] * c02;
  float id  = 1.0f / det;
  r[0] = c00 * id;
  r[1] = (a[2] * a[7] - a[1] * a[8]) * id;
  r[2] = (a[1] * a[5] - a[2] * a[4]) * id;
  r[3] = c01 * id;
  r[4] = (a[0] * a[8] - a[2] * a[6]) * id;
  r[5] = (a[2] * a[3] - a[0] * a[5]) * id;
  r[6] = c02 * id;
  r[7] = (a[1] * a[6] - a[0] * a[7]) * id;
  r[8] = (a[0] * a[4] - a[1] * a[3]) * id;
}

__device__ inline void build_mats(int i,
                                  const float* __restrict__ rots,
                                  const float* __restrict__ trans,
                                  const float* __restrict__ intrins,
                                  const float* __restrict__ post_rots,
                                  const float* __restrict__ post_trans,
                                  float* __restrict__ o) {
#pragma clang fp contract(off)
  const float eps = 1e-6f;
  float m[9], inv_post[9], ki[9];

  for (int k = 0; k < 9; ++k) m[k] = post_rots[i * 9 + k];
  m[0] += eps; m[4] += eps; m[8] += eps;
  inv3x3(m, inv_post);

  for (int k = 0; k < 9; ++k) m[k] = intrins[i * 9 + k];
  m[0] += eps; m[4] += eps; m[8] += eps;
  inv3x3(m, ki);

  for (int k = 0; k < 9; ++k) o[k] = inv_post[k];
  for (int r = 0; r < 3; ++r)
    for (int c = 0; c < 3; ++c)
      o[9 + r * 3 + c] = rots[i * 9 + r * 3 + 0] * ki[0 * 3 + c]
                       + rots[i * 9 + r * 3 + 1] * ki[1 * 3 + c]
                       + rots[i * 9 + r * 3 + 2] * ki[2 * 3 + c];
  for (int k = 0; k < 3; ++k) o[18 + k] = trans[i * 3 + k];
  for (int k = 0; k < 3; ++k) o[21 + k] = post_trans[i * 3 + k];
}

__device__ inline int point_voxel(int wid, const float* __restrict__ mats) {
#pragma clang fp contract(off)
  int t  = wid;
  int w  = t % FW;  t /= FW;
  int h  = t % FH;  t /= FH;
  int dd = t % D;   t /= D;
  int n  = t % N;
  int b  = t / N;

  const float* M = mats + (b * N + n) * MAT_STRIDE;

  float u   = (float)w * (351.0f / 21.0f);
  float v   = (float)h * (127.0f / 7.0f);
  float dep = 4.0f + (float)dd;

  float p0 = u - M[21], p1 = v - M[22], p2 = dep - M[23];

  float q0 = M[0] * p0 + M[1] * p1 + M[2] * p2;
  float q1 = M[3] * p0 + M[4] * p1 + M[5] * p2;
  float q2 = M[6] * p0 + M[7] * p1 + M[8] * p2;

  float sd;
  if (fabsf(q2) < 1e-6f) {
    float t2 = q2 + 1e-6f;
    float s  = (t2 > 0.0f) ? 1.0f : ((t2 < 0.0f) ? -1.0f : 0.0f);
    sd = 1e-6f * s;
  } else {
    sd = q2;
  }
  float r0 = q0 * sd, r1 = q1 * sd, r2 = sd;

  float g0 = (M[9]  * r0 + M[10] * r1 + M[11] * r2) + M[18];
  float g1 = (M[12] * r0 + M[13] * r1 + M[14] * r2) + M[19];
  float g2 = (M[15] * r0 + M[16] * r1 + M[17] * r2) + M[20];

  float gnx = (g0 + 50.0f) / 0.5f;
  float gny = (g1 + 50.0f) / 0.5f;
  float gnz = (g2 + 10.0f) / 20.0f;
  int gx = (int)gnx;
  int gy = (int)gny;
  int gz = (int)gnz;

  if (gx < 0 || gx >= NX0 || gy < 0 || gy >= NX1 || gz < 0 || gz >= NX2)
    return -1;
  return b * NVOX + gx * NX1 + gy;   // global voxel id (gz == 0)
}

// Pass 0: clear per-tile counts + overflow counter (5001 ints).
__global__ __launch_bounds__(256) void clear_counts(int* __restrict__ counts) {
  int i = blockIdx.x * 256 + threadIdx.x;
  if (i <= NTILES) counts[i] = 0;
}

// Pass 1: bin kept points by output tile. Entry packs pid (19b) | v_in_tile (6b).
__global__ __launch_bounds__(256) void bin_points(const float* __restrict__ rots,
                                                  const float* __restrict__ trans,
                                                  const float* __restrict__ intrins,
                                                  const float* __restrict__ post_rots,
                                                  const float* __restrict__ post_trans,
                                                  int* __restrict__ counts,
                                                  int* __restrict__ bins,
                                                  int* __restrict__ ovf) {
  __shared__ float smats[B * N * MAT_STRIDE];
  int t = threadIdx.x;
  if (t < B * N)
    build_mats(t, rots, trans, intrins, post_rots, post_trans, smats + t * MAT_STRIDE);
  __syncthreads();

  int pid = blockIdx.x * 256 + t;           // NPTS is a multiple of 256
  int v = point_voxel(pid, smats);
  if (v < 0) return;

  int bt  = v >> 6;                         // tile id (NVOX % 64 == 0)
  int vin = v & 63;
  int idx = atomicAdd(&counts[bt], 1);
  if (idx < CAP) {
    bins[(size_t)bt * CAP + idx] = pid | (vin << 19);
  } else {
    int o = atomicAdd(&counts[NTILES], 1);  // overflow counter
    if (o < NPTS) ovf[o] = pid;
  }
}

// Pass 2: one block per output tile (64 voxels x 64 channels). Accumulate
// contributions in a zeroed LDS tile via LDS float atomics (lane == channel:
// conflict-free), then write the final (B,C,NVOX) layout directly.
__global__ __launch_bounds__(256) void gather_tiles(const float* __restrict__ x,
                                                    const int* __restrict__ counts,
                                                    const int* __restrict__ bins,
                                                    float* __restrict__ out) {
  __shared__ float tile[64][65];
  int bt   = blockIdx.x;                    // 0..NTILES-1
  int b    = bt / VTILES;
  int v0   = (bt % VTILES) * 64;
  int t    = threadIdx.x;
  int lane = t & 63;

  int cnt = counts[bt];

  int v4 = (t & 15) * 4;                    // voxel offset for output writes
  int cr = t >> 4;                          // 0..15

  if (cnt == 0) {
    float4 z = make_float4(0.f, 0.f, 0.f, 0.f);
    for (int k = 0; k < 4; ++k)
      *(float4*)(out + ((size_t)(b * C + cr + k * 16)) * NVOX + v0 + v4) = z;
    return;
  }

  for (int i = t; i < 64 * 64; i += 256) tile[i >> 6][i & 63] = 0.f;
  __syncthreads();

  int n = cnt < CAP ? cnt : CAP;
  int pslot = t >> 6;                       // 4 points processed per iteration
  for (int i = 0; i < n; i += 4) {
    int j = i + pslot;
    if (j < n) {
      int e   = bins[(size_t)bt * CAP + j];
      int pid = e & 0x7FFFF;
      int vin = (e >> 19) & 63;
      float val = x[(size_t)pid * C + lane];   // 256B coalesced per wave
      atomicAdd(&tile[vin][lane], val);        // LDS atomic, banks distinct
    }
  }
  __syncthreads();

  for (int k = 0; k < 4; ++k) {
    int c = cr + k * 16;
    float4 vv;
    vv.x = tile[v4 + 0][c];
    vv.y = tile[v4 + 1][c];
    vv.z = tile[v4 + 2][c];
    vv.w = tile[v4 + 3][c];
    *(float4*)(out + ((size_t)(b * C + c)) * NVOX + v0 + v4) = vv;
  }
}

// Pass 3: drain overflow list (normally empty) with direct atomics onto out.
__global__ __launch_bounds__(256) void overflow_splat(const float* __restrict__ x,
                                                      const float* __restrict__ rots,
                                                      const float* __restrict__ trans,
                                                      const float* __restrict__ intrins,
                                                      const float* __restrict__ post_rots,
                                                      const float* __restrict__ post_trans,
                                                      const int* __restrict__ counts,
                                                      const int* __restrict__ ovf,
                                                      float* __restrict__ out) {
  int n = counts[NTILES];
  if (n <= 0) return;
  if (n > NPTS) n = NPTS;

  __shared__ float smats[B * N * MAT_STRIDE];
  int t = threadIdx.x;
  if (t < B * N)
    build_mats(t, rots, trans, intrins, post_rots, post_trans, smats + t * MAT_STRIDE);
  __syncthreads();

  int lane = t & 63;
  int wid  = (blockIdx.x * 256 + t) >> 6;
  int nw   = (gridDim.x * 256) >> 6;
  for (int i = wid; i < n; i += nw) {
    int pid = ovf[i];
    int v = point_voxel(pid, smats);
    if (v < 0) continue;
    int b   = v / NVOX;
    int loc = v % NVOX;
    atomicAdd(out + ((size_t)(b * C + lane)) * NVOX + loc, x[(size_t)pid * C + lane]);
  }
}

// ---- minimal-ws fallback: direct atomics into out ----
__global__ void prep_mats(const float* __restrict__ rots,
                          const float* __restrict__ trans,
                          const float* __restrict__ intrins,
                          const float* __restrict__ post_rots,
                          const float* __restrict__ post_trans,
                          float* __restrict__ mats) {
  int i = blockIdx.x * blockDim.x + threadIdx.x;
  if (i >= B * N) return;
  build_mats(i, rots, trans, intrins, post_rots, post_trans, mats + i * MAT_STRIDE);
}

__global__ __launch_bounds__(256) void lss_splat_direct(const float* __restrict__ x,
                                                        const float* __restrict__ mats,
                                                        float* __restrict__ out) {
  int wid  = blockIdx.x * 4 + (threadIdx.x >> 6);
  if (wid >= NPTS) return;
  int lane = threadIdx.x & 63;
  int voxel = point_voxel(wid, mats);
  if (voxel < 0) return;
  int b = voxel / NVOX;
  int v = voxel % NVOX;
  float val = x[(size_t)wid * C + lane];
  size_t oidx = ((size_t)(b * C + lane)) * NVOX + v;
  atomicAdd(out + oidx, val);
}

}  // namespace

extern "C" void kernel_launch(void* const* d_in, const int* in_sizes, int n_in,
                              void* d_out, int out_size, void* d_ws, size_t ws_size,
                              hipStream_t stream) {
  const float* x          = (const float*)d_in[0];
  const float* rots       = (const float*)d_in[1];
  const float* trans      = (const float*)d_in[2];
  const float* intrins    = (const float*)d_in[3];
  const float* post_rots  = (const float*)d_in[4];
  const float* post_trans = (const float*)d_in[5];
  float* out = (float*)d_out;

  // ws layout: counts[NTILES+1] | bins[NTILES*CAP] | ovf[NPTS]
  const size_t bins_off = (((size_t)(NTILES + 1) * sizeof(int)) + 255) & ~(size_t)255;
  const size_t ovf_off  = bins_off + (size_t)NTILES * CAP * sizeof(int);
  const size_t need     = ovf_off + (size_t)NPTS * sizeof(int);

  if (ws_size >= need) {
    int* counts = (int*)d_ws;
    int* bins   = (int*)((char*)d_ws + bins_off);
    int* ovf    = (int*)((char*)d_ws + ovf_off);

    clear_counts<<<(NTILES + 1 + 255) / 256, 256, 0, stream>>>(counts);
    bin_points<<<NPTS / 256, 256, 0, stream>>>(rots, trans, intrins, post_rots,
                                               post_trans, counts, bins, ovf);
    gather_tiles<<<NTILES, 256, 0, stream>>>(x, counts, bins, out);
    overflow_splat<<<16, 256, 0, stream>>>(x, rots, trans, intrins, post_rots,
                                           post_trans, counts, ovf, out);
  } else {
    float* mats = (float*)d_ws;  // 4.6 KB
    hipMemsetAsync(d_out, 0, (size_t)out_size * sizeof(float), stream);
    prep_mats<<<1, 64, 0, stream>>>(rots, trans, intrins, post_rots, post_trans, mats);
    lss_splat_direct<<<(NPTS + 3) / 4, 256, 0, stream>>>(x, mats, out);
  }
}

// Round 7
// 99.388 us; speedup vs baseline: 1.2661x; 1.2661x over previous
//
#include <hip/hip_runtime.h>
#include <math.h>

namespace {

constexpr int B  = 8;
constexpr int N  = 6;
constexpr int D  = 41;
constexpr int FH = 8;    // 128/16
constexpr int FW = 22;   // 352/16
constexpr int C  = 64;
constexpr int NPTS = B * N * D * FH * FW;   // 346368 = 1353 * 256
constexpr int NX0 = 200, NX1 = 200, NX2 = 1;
constexpr int NVOX = NX0 * NX1;             // 40000 voxels per batch (gz==0)
constexpr int MAT_STRIDE = 24;
constexpr int VTILES = NVOX / 64;           // 625 tiles per batch
constexpr int NTILES = B * VTILES;          // 5000
constexpr int CAP    = 4096;                // bin capacity per tile (ints)

__device__ inline void inv3x3(const float a[9], float r[9]) {
  float c00 = a[4] * a[8] - a[5] * a[7];
  float c01 = a[5] * a[6] - a[3] * a[8];
  float c02 = a[3] * a[7] - a[4] * a[6];
  float det = a[0] * c00 + a[1] * c01 + a[2] * c02;
  float id  = 1.0f / det;
  r[0] = c00 * id;
  r[1] = (a[2] * a[7] - a[1] * a[8]) * id;
  r[2] = (a[1] * a[5] - a[2] * a[4]) * id;
  r[3] = c01 * id;
  r[4] = (a[0] * a[8] - a[2] * a[6]) * id;
  r[5] = (a[2] * a[3] - a[0] * a[5]) * id;
  r[6] = c02 * id;
  r[7] = (a[1] * a[6] - a[0] * a[7]) * id;
  r[8] = (a[0] * a[4] - a[1] * a[3]) * id;
}

__device__ inline void build_mats(int i,
                                  const float* __restrict__ rots,
                                  const float* __restrict__ trans,
                                  const float* __restrict__ intrins,
                                  const float* __restrict__ post_rots,
                                  const float* __restrict__ post_trans,
                                  float* __restrict__ o) {
#pragma clang fp contract(off)
  const float eps = 1e-6f;
  float m[9], inv_post[9], ki[9];

  for (int k = 0; k < 9; ++k) m[k] = post_rots[i * 9 + k];
  m[0] += eps; m[4] += eps; m[8] += eps;
  inv3x3(m, inv_post);

  for (int k = 0; k < 9; ++k) m[k] = intrins[i * 9 + k];
  m[0] += eps; m[4] += eps; m[8] += eps;
  inv3x3(m, ki);

  for (int k = 0; k < 9; ++k) o[k] = inv_post[k];
  for (int r = 0; r < 3; ++r)
    for (int c = 0; c < 3; ++c)
      o[9 + r * 3 + c] = rots[i * 9 + r * 3 + 0] * ki[0 * 3 + c]
                       + rots[i * 9 + r * 3 + 1] * ki[1 * 3 + c]
                       + rots[i * 9 + r * 3 + 2] * ki[2 * 3 + c];
  for (int k = 0; k < 3; ++k) o[18 + k] = trans[i * 3 + k];
  for (int k = 0; k < 3; ++k) o[21 + k] = post_trans[i * 3 + k];
}

__device__ inline int point_voxel(int wid, const float* __restrict__ mats) {
#pragma clang fp contract(off)
  int t  = wid;
  int w  = t % FW;  t /= FW;
  int h  = t % FH;  t /= FH;
  int dd = t % D;   t /= D;
  int n  = t % N;
  int b  = t / N;

  const float* M = mats + (b * N + n) * MAT_STRIDE;

  float u   = (float)w * (351.0f / 21.0f);
  float v   = (float)h * (127.0f / 7.0f);
  float dep = 4.0f + (float)dd;

  float p0 = u - M[21], p1 = v - M[22], p2 = dep - M[23];

  float q0 = M[0] * p0 + M[1] * p1 + M[2] * p2;
  float q1 = M[3] * p0 + M[4] * p1 + M[5] * p2;
  float q2 = M[6] * p0 + M[7] * p1 + M[8] * p2;

  float sd;
  if (fabsf(q2) < 1e-6f) {
    float t2 = q2 + 1e-6f;
    float s  = (t2 > 0.0f) ? 1.0f : ((t2 < 0.0f) ? -1.0f : 0.0f);
    sd = 1e-6f * s;
  } else {
    sd = q2;
  }
  float r0 = q0 * sd, r1 = q1 * sd, r2 = sd;

  float g0 = (M[9]  * r0 + M[10] * r1 + M[11] * r2) + M[18];
  float g1 = (M[12] * r0 + M[13] * r1 + M[14] * r2) + M[19];
  float g2 = (M[15] * r0 + M[16] * r1 + M[17] * r2) + M[20];

  float gnx = (g0 + 50.0f) / 0.5f;
  float gny = (g1 + 50.0f) / 0.5f;
  float gnz = (g2 + 10.0f) / 20.0f;
  int gx = (int)gnx;
  int gy = (int)gny;
  int gz = (int)gnz;

  if (gx < 0 || gx >= NX0 || gy < 0 || gy >= NX1 || gz < 0 || gz >= NX2)
    return -1;
  return b * NVOX + gx * NX1 + gy;   // global voxel id (gz == 0)
}

// Pass 0: clear per-tile counts + overflow counter (5001 ints).
__global__ __launch_bounds__(256) void clear_counts(int* __restrict__ counts) {
  int i = blockIdx.x * 256 + threadIdx.x;
  if (i <= NTILES) counts[i] = 0;
}

// Pass 1: bin kept points by output tile. Entry packs pid (19b) | v_in_tile (6b).
__global__ __launch_bounds__(256) void bin_points(const float* __restrict__ rots,
                                                  const float* __restrict__ trans,
                                                  const float* __restrict__ intrins,
                                                  const float* __restrict__ post_rots,
                                                  const float* __restrict__ post_trans,
                                                  int* __restrict__ counts,
                                                  int* __restrict__ bins,
                                                  int* __restrict__ ovf) {
  __shared__ float smats[B * N * MAT_STRIDE];
  int t = threadIdx.x;
  if (t < B * N)
    build_mats(t, rots, trans, intrins, post_rots, post_trans, smats + t * MAT_STRIDE);
  __syncthreads();

  int pid = blockIdx.x * 256 + t;           // NPTS is a multiple of 256
  int v = point_voxel(pid, smats);
  if (v < 0) return;

  int bt  = v >> 6;                         // tile id (NVOX % 64 == 0)
  int vin = v & 63;
  int idx = atomicAdd(&counts[bt], 1);
  if (idx < CAP) {
    bins[(size_t)bt * CAP + idx] = pid | (vin << 19);
  } else {
    int o = atomicAdd(&counts[NTILES], 1);  // overflow counter
    if (o < NPTS) ovf[o] = pid;
  }
}

// Pass 2: one 1024-thread block per output tile (64 voxels x 64 channels).
// 16 waves; each wave pipelines 16 points at a time (coalesced bin-entry read,
// shfl broadcast, 16 independent x loads in flight, then 16 LDS atomics).
// Tile accumulates in LDS; final (B,C,NVOX) write is one float4 per thread.
__global__ __launch_bounds__(1024) void gather_tiles(const float* __restrict__ x,
                                                     const int* __restrict__ counts,
                                                     const int* __restrict__ bins,
                                                     float* __restrict__ out) {
  __shared__ float tile[64][65];
  int bt   = blockIdx.x;                    // 0..NTILES-1
  int b    = bt / VTILES;
  int v0   = (bt % VTILES) * 64;
  int t    = threadIdx.x;
  int lane = t & 63;
  int wv   = t >> 6;                        // wave id, 0..15

  int cnt = counts[bt];

  // output mapping: one float4 per thread covers the full 64x64 tile
  int v4 = (t & 15) * 4;                    // voxel group
  int c  = t >> 4;                          // channel 0..63

  if (cnt == 0) {
    *(float4*)(out + ((size_t)(b * C + c)) * NVOX + v0 + v4) =
        make_float4(0.f, 0.f, 0.f, 0.f);
    return;
  }

  // zero LDS tile
  for (int i = t; i < 64 * 65; i += 1024) ((float*)tile)[i] = 0.f;
  __syncthreads();

  int n = cnt < CAP ? cnt : CAP;
  const int* tb = bins + (size_t)bt * CAP;

  // each wave processes a strided chunk of 16 entries per iteration
  for (int j0 = wv * 16; j0 < n; j0 += 16 * 16) {
    int e = -1;
    if (lane < 16 && j0 + lane < n) e = tb[j0 + lane];

    float vals[16];
    int   vins[16];
    bool  ok[16];
#pragma unroll
    for (int k = 0; k < 16; ++k) {
      int ek  = __shfl(e, k);
      ok[k]   = ek >= 0;
      vins[k] = (ek >> 19) & 63;
      int pid = ek & 0x7FFFF;
      vals[k] = ok[k] ? x[(size_t)pid * C + lane] : 0.f;   // 16 loads in flight
    }
#pragma unroll
    for (int k = 0; k < 16; ++k)
      if (ok[k]) atomicAdd(&tile[vins[k]][lane], vals[k]);
  }
  __syncthreads();

  float4 vv;
  vv.x = tile[v4 + 0][c];
  vv.y = tile[v4 + 1][c];
  vv.z = tile[v4 + 2][c];
  vv.w = tile[v4 + 3][c];
  *(float4*)(out + ((size_t)(b * C + c)) * NVOX + v0 + v4) = vv;
}

// Pass 3: drain overflow list (normally empty) with direct atomics onto out.
__global__ __launch_bounds__(256) void overflow_splat(const float* __restrict__ x,
                                                      const float* __restrict__ rots,
                                                      const float* __restrict__ trans,
                                                      const float* __restrict__ intrins,
                                                      const float* __restrict__ post_rots,
                                                      const float* __restrict__ post_trans,
                                                      const int* __restrict__ counts,
                                                      const int* __restrict__ ovf,
                                                      float* __restrict__ out) {
  int n = counts[NTILES];
  if (n <= 0) return;
  if (n > NPTS) n = NPTS;

  __shared__ float smats[B * N * MAT_STRIDE];
  int t = threadIdx.x;
  if (t < B * N)
    build_mats(t, rots, trans, intrins, post_rots, post_trans, smats + t * MAT_STRIDE);
  __syncthreads();

  int lane = t & 63;
  int wid  = (blockIdx.x * 256 + t) >> 6;
  int nw   = (gridDim.x * 256) >> 6;
  for (int i = wid; i < n; i += nw) {
    int pid = ovf[i];
    int v = point_voxel(pid, smats);
    if (v < 0) continue;
    int b   = v / NVOX;
    int loc = v % NVOX;
    atomicAdd(out + ((size_t)(b * C + lane)) * NVOX + loc, x[(size_t)pid * C + lane]);
  }
}

// ---- minimal-ws fallback: direct atomics into out ----
__global__ void prep_mats(const float* __restrict__ rots,
                          const float* __restrict__ trans,
                          const float* __restrict__ intrins,
                          const float* __restrict__ post_rots,
                          const float* __restrict__ post_trans,
                          float* __restrict__ mats) {
  int i = blockIdx.x * blockDim.x + threadIdx.x;
  if (i >= B * N) return;
  build_mats(i, rots, trans, intrins, post_rots, post_trans, mats + i * MAT_STRIDE);
}

__global__ __launch_bounds__(256) void lss_splat_direct(const float* __restrict__ x,
                                                        const float* __restrict__ mats,
                                                        float* __restrict__ out) {
  int wid  = blockIdx.x * 4 + (threadIdx.x >> 6);
  if (wid >= NPTS) return;
  int lane = threadIdx.x & 63;
  int voxel = point_voxel(wid, mats);
  if (voxel < 0) return;
  int b = voxel / NVOX;
  int v = voxel % NVOX;
  float val = x[(size_t)wid * C + lane];
  size_t oidx = ((size_t)(b * C + lane)) * NVOX + v;
  atomicAdd(out + oidx, val);
}

}  // namespace

extern "C" void kernel_launch(void* const* d_in, const int* in_sizes, int n_in,
                              void* d_out, int out_size, void* d_ws, size_t ws_size,
                              hipStream_t stream) {
  const float* x          = (const float*)d_in[0];
  const float* rots       = (const float*)d_in[1];
  const float* trans      = (const float*)d_in[2];
  const float* intrins    = (const float*)d_in[3];
  const float* post_rots  = (const float*)d_in[4];
  const float* post_trans = (const float*)d_in[5];
  float* out = (float*)d_out;

  // ws layout: counts[NTILES+1] | bins[NTILES*CAP] | ovf[NPTS]
  const size_t bins_off = (((size_t)(NTILES + 1) * sizeof(int)) + 255) & ~(size_t)255;
  const size_t ovf_off  = bins_off + (size_t)NTILES * CAP * sizeof(int);
  const size_t need     = ovf_off + (size_t)NPTS * sizeof(int);

  if (ws_size >= need) {
    int* counts = (int*)d_ws;
    int* bins   = (int*)((char*)d_ws + bins_off);
    int* ovf    = (int*)((char*)d_ws + ovf_off);

    clear_counts<<<(NTILES + 1 + 255) / 256, 256, 0, stream>>>(counts);
    bin_points<<<NPTS / 256, 256, 0, stream>>>(rots, trans, intrins, post_rots,
                                               post_trans, counts, bins, ovf);
    gather_tiles<<<NTILES, 1024, 0, stream>>>(x, counts, bins, out);
    overflow_splat<<<16, 256, 0, stream>>>(x, rots, trans, intrins, post_rots,
                                           post_trans, counts, ovf, out);
  } else {
    float* mats = (float*)d_ws;  // 4.6 KB
    hipMemsetAsync(d_out, 0, (size_t)out_size * sizeof(float), stream);
    prep_mats<<<1, 64, 0, stream>>>(rots, trans, intrins, post_rots, post_trans, mats);
    lss_splat_direct<<<(NPTS + 3) / 4, 256, 0, stream>>>(x, mats, out);
  }
}

// Round 8
// 75.907 us; speedup vs baseline: 1.6577x; 1.3093x over previous
//
#include <hip/hip_runtime.h>
#include <math.h>

namespace {

constexpr int B  = 8;
constexpr int N  = 6;
constexpr int D  = 41;
constexpr int FH = 8;    // 128/16
constexpr int FW = 22;   // 352/16
constexpr int C  = 64;
constexpr int NPTS = B * N * D * FH * FW;   // 346368 = 1353 * 256
constexpr int NX0 = 200, NX1 = 200, NX2 = 1;
constexpr int NVOX = NX0 * NX1;             // 40000 voxels per batch (gz==0)
constexpr int MAT_STRIDE = 24;
constexpr int VTILES = NVOX / 64;           // 625 tiles per batch
constexpr int NTILES = B * VTILES;          // 5000
constexpr int CAP    = 4096;                // bin capacity per tile (ints)
constexpr int GBLOCKS = 512;                // gather blocks: 2 per CU, co-resident

__device__ inline void inv3x3(const float a[9], float r[9]) {
  float c00 = a[4] * a[8] - a[5] * a[7];
  float c01 = a[5] * a[6] - a[3] * a[8];
  float c02 = a[3] * a[7] - a[4] * a[6];
  float det = a[0] * c00 + a[1] * c01 + a[2] * c02;
  float id  = 1.0f / det;
  r[0] = c00 * id;
  r[1] = (a[2] * a[7] - a[1] * a[8]) * id;
  r[2] = (a[1] * a[5] - a[2] * a[4]) * id;
  r[3] = c01 * id;
  r[4] = (a[0] * a[8] - a[2] * a[6]) * id;
  r[5] = (a[2] * a[3] - a[0] * a[5]) * id;
  r[6] = c02 * id;
  r[7] = (a[1] * a[6] - a[0] * a[7]) * id;
  r[8] = (a[0] * a[4] - a[1] * a[3]) * id;
}

__device__ inline void build_mats(int i,
                                  const float* __restrict__ rots,
                                  const float* __restrict__ trans,
                                  const float* __restrict__ intrins,
                                  const float* __restrict__ post_rots,
                                  const float* __restrict__ post_trans,
                                  float* __restrict__ o) {
#pragma clang fp contract(off)
  const float eps = 1e-6f;
  float m[9], inv_post[9], ki[9];

  for (int k = 0; k < 9; ++k) m[k] = post_rots[i * 9 + k];
  m[0] += eps; m[4] += eps; m[8] += eps;
  inv3x3(m, inv_post);

  for (int k = 0; k < 9; ++k) m[k] = intrins[i * 9 + k];
  m[0] += eps; m[4] += eps; m[8] += eps;
  inv3x3(m, ki);

  for (int k = 0; k < 9; ++k) o[k] = inv_post[k];
  for (int r = 0; r < 3; ++r)
    for (int c = 0; c < 3; ++c)
      o[9 + r * 3 + c] = rots[i * 9 + r * 3 + 0] * ki[0 * 3 + c]
                       + rots[i * 9 + r * 3 + 1] * ki[1 * 3 + c]
                       + rots[i * 9 + r * 3 + 2] * ki[2 * 3 + c];
  for (int k = 0; k < 3; ++k) o[18 + k] = trans[i * 3 + k];
  for (int k = 0; k < 3; ++k) o[21 + k] = post_trans[i * 3 + k];
}

__device__ inline int point_voxel(int wid, const float* __restrict__ mats) {
#pragma clang fp contract(off)
  int t  = wid;
  int w  = t % FW;  t /= FW;
  int h  = t % FH;  t /= FH;
  int dd = t % D;   t /= D;
  int n  = t % N;
  int b  = t / N;

  const float* M = mats + (b * N + n) * MAT_STRIDE;

  float u   = (float)w * (351.0f / 21.0f);
  float v   = (float)h * (127.0f / 7.0f);
  float dep = 4.0f + (float)dd;

  float p0 = u - M[21], p1 = v - M[22], p2 = dep - M[23];

  float q0 = M[0] * p0 + M[1] * p1 + M[2] * p2;
  float q1 = M[3] * p0 + M[4] * p1 + M[5] * p2;
  float q2 = M[6] * p0 + M[7] * p1 + M[8] * p2;

  float sd;
  if (fabsf(q2) < 1e-6f) {
    float t2 = q2 + 1e-6f;
    float s  = (t2 > 0.0f) ? 1.0f : ((t2 < 0.0f) ? -1.0f : 0.0f);
    sd = 1e-6f * s;
  } else {
    sd = q2;
  }
  float r0 = q0 * sd, r1 = q1 * sd, r2 = sd;

  float g0 = (M[9]  * r0 + M[10] * r1 + M[11] * r2) + M[18];
  float g1 = (M[12] * r0 + M[13] * r1 + M[14] * r2) + M[19];
  float g2 = (M[15] * r0 + M[16] * r1 + M[17] * r2) + M[20];

  float gnx = (g0 + 50.0f) / 0.5f;
  float gny = (g1 + 50.0f) / 0.5f;
  float gnz = (g2 + 10.0f) / 20.0f;
  int gx = (int)gnx;
  int gy = (int)gny;
  int gz = (int)gnz;

  if (gx < 0 || gx >= NX0 || gy < 0 || gy >= NX1 || gz < 0 || gz >= NX2)
    return -1;
  return b * NVOX + gx * NX1 + gy;   // global voxel id (gz == 0)
}

// Pass 0: clear per-tile counts + overflow counter (5001 ints).
__global__ __launch_bounds__(256) void clear_counts(int* __restrict__ counts) {
  int i = blockIdx.x * 256 + threadIdx.x;
  if (i <= NTILES) counts[i] = 0;
}

// Pass 1: bin kept points by output tile. Entry packs pid (19b) | v_in_tile (6b).
__global__ __launch_bounds__(256) void bin_points(const float* __restrict__ rots,
                                                  const float* __restrict__ trans,
                                                  const float* __restrict__ intrins,
                                                  const float* __restrict__ post_rots,
                                                  const float* __restrict__ post_trans,
                                                  int* __restrict__ counts,
                                                  int* __restrict__ bins,
                                                  int* __restrict__ ovf) {
  __shared__ float smats[B * N * MAT_STRIDE];
  int t = threadIdx.x;
  if (t < B * N)
    build_mats(t, rots, trans, intrins, post_rots, post_trans, smats + t * MAT_STRIDE);
  __syncthreads();

  int pid = blockIdx.x * 256 + t;           // NPTS is a multiple of 256
  int v = point_voxel(pid, smats);
  if (v < 0) return;

  int bt  = v >> 6;                         // tile id (NVOX % 64 == 0)
  int vin = v & 63;
  int idx = atomicAdd(&counts[bt], 1);
  if (idx < CAP) {
    bins[(size_t)bt * CAP + idx] = pid | (vin << 19);
  } else {
    int o = atomicAdd(&counts[NTILES], 1);  // overflow counter
    if (o < NPTS) ovf[o] = pid;
  }
}

// Pass 2: persistent gather. GBLOCKS co-resident 1024-thread blocks grid-stride
// over the 5000 tiles: empty tiles stream zeros with no block-churn overhead;
// hot tiles (consecutive bt) land on different blocks. Per tile: accumulate in
// LDS (16 waves x 16-deep pipelined point loads, LDS atomics with lane=channel
// conflict-free), then one float4/thread write of the final (B,C,NVOX) layout.
__global__ __launch_bounds__(1024) void gather_tiles(const float* __restrict__ x,
                                                     const int* __restrict__ counts,
                                                     const int* __restrict__ bins,
                                                     float* __restrict__ out) {
  __shared__ float tile[64][65];
  int t    = threadIdx.x;
  int lane = t & 63;
  int wv   = t >> 6;                        // wave id, 0..15
  int v4   = (t & 15) * 4;                  // voxel group for output writes
  int c    = t >> 4;                        // channel 0..63

  for (int bt = blockIdx.x; bt < NTILES; bt += GBLOCKS) {
    int b  = bt / VTILES;
    int v0 = (bt % VTILES) * 64;
    int cnt = counts[bt];

    if (cnt == 0) {
      *(float4*)(out + ((size_t)(b * C + c)) * NVOX + v0 + v4) =
          make_float4(0.f, 0.f, 0.f, 0.f);
      continue;                             // block-uniform branch
    }

    __syncthreads();                        // LDS reuse guard (prev tile's reads done)
    for (int i = t; i < 64 * 65; i += 1024) ((float*)tile)[i] = 0.f;
    __syncthreads();

    int n = cnt < CAP ? cnt : CAP;
    const int* tb = bins + (size_t)bt * CAP;

    for (int j0 = wv * 16; j0 < n; j0 += 16 * 16) {
      int e = -1;
      if (lane < 16 && j0 + lane < n) e = tb[j0 + lane];

      float vals[16];
      int   vins[16];
      bool  ok[16];
#pragma unroll
      for (int k = 0; k < 16; ++k) {
        int ek  = __shfl(e, k);
        ok[k]   = ek >= 0;
        vins[k] = (ek >> 19) & 63;
        int pid = ek & 0x7FFFF;
        vals[k] = ok[k] ? x[(size_t)pid * C + lane] : 0.f;   // 16 loads in flight
      }
#pragma unroll
      for (int k = 0; k < 16; ++k)
        if (ok[k]) atomicAdd(&tile[vins[k]][lane], vals[k]);
    }
    __syncthreads();

    float4 vv;
    vv.x = tile[v4 + 0][c];
    vv.y = tile[v4 + 1][c];
    vv.z = tile[v4 + 2][c];
    vv.w = tile[v4 + 3][c];
    *(float4*)(out + ((size_t)(b * C + c)) * NVOX + v0 + v4) = vv;
  }
}

// Pass 3: drain overflow list (normally empty) with direct atomics onto out.
// Must remain a separate dispatch: these atomics race with gather's plain
// stores if merged into the same kernel.
__global__ __launch_bounds__(256) void overflow_splat(const float* __restrict__ x,
                                                      const float* __restrict__ rots,
                                                      const float* __restrict__ trans,
                                                      const float* __restrict__ intrins,
                                                      const float* __restrict__ post_rots,
                                                      const float* __restrict__ post_trans,
                                                      const int* __restrict__ counts,
                                                      const int* __restrict__ ovf,
                                                      float* __restrict__ out) {
  int n = counts[NTILES];
  if (n <= 0) return;
  if (n > NPTS) n = NPTS;

  __shared__ float smats[B * N * MAT_STRIDE];
  int t = threadIdx.x;
  if (t < B * N)
    build_mats(t, rots, trans, intrins, post_rots, post_trans, smats + t * MAT_STRIDE);
  __syncthreads();

  int lane = t & 63;
  int wid  = (blockIdx.x * 256 + t) >> 6;
  int nw   = (gridDim.x * 256) >> 6;
  for (int i = wid; i < n; i += nw) {
    int pid = ovf[i];
    int v = point_voxel(pid, smats);
    if (v < 0) continue;
    int b   = v / NVOX;
    int loc = v % NVOX;
    atomicAdd(out + ((size_t)(b * C + lane)) * NVOX + loc, x[(size_t)pid * C + lane]);
  }
}

// ---- minimal-ws fallback: direct atomics into out ----
__global__ void prep_mats(const float* __restrict__ rots,
                          const float* __restrict__ trans,
                          const float* __restrict__ intrins,
                          const float* __restrict__ post_rots,
                          const float* __restrict__ post_trans,
                          float* __restrict__ mats) {
  int i = blockIdx.x * blockDim.x + threadIdx.x;
  if (i >= B * N) return;
  build_mats(i, rots, trans, intrins, post_rots, post_trans, mats + i * MAT_STRIDE);
}

__global__ __launch_bounds__(256) void lss_splat_direct(const float* __restrict__ x,
                                                        const float* __restrict__ mats,
                                                        float* __restrict__ out) {
  int wid  = blockIdx.x * 4 + (threadIdx.x >> 6);
  if (wid >= NPTS) return;
  int lane = threadIdx.x & 63;
  int voxel = point_voxel(wid, mats);
  if (voxel < 0) return;
  int b = voxel / NVOX;
  int v = voxel % NVOX;
  float val = x[(size_t)wid * C + lane];
  size_t oidx = ((size_t)(b * C + lane)) * NVOX + v;
  atomicAdd(out + oidx, val);
}

}  // namespace

extern "C" void kernel_launch(void* const* d_in, const int* in_sizes, int n_in,
                              void* d_out, int out_size, void* d_ws, size_t ws_size,
                              hipStream_t stream) {
  const float* x          = (const float*)d_in[0];
  const float* rots       = (const float*)d_in[1];
  const float* trans      = (const float*)d_in[2];
  const float* intrins    = (const float*)d_in[3];
  const float* post_rots  = (const float*)d_in[4];
  const float* post_trans = (const float*)d_in[5];
  float* out = (float*)d_out;

  // ws layout: counts[NTILES+1] | bins[NTILES*CAP] | ovf[NPTS]
  const size_t bins_off = (((size_t)(NTILES + 1) * sizeof(int)) + 255) & ~(size_t)255;
  const size_t ovf_off  = bins_off + (size_t)NTILES * CAP * sizeof(int);
  const size_t need     = ovf_off + (size_t)NPTS * sizeof(int);

  if (ws_size >= need) {
    int* counts = (int*)d_ws;
    int* bins   = (int*)((char*)d_ws + bins_off);
    int* ovf    = (int*)((char*)d_ws + ovf_off);

    clear_counts<<<(NTILES + 1 + 255) / 256, 256, 0, stream>>>(counts);
    bin_points<<<NPTS / 256, 256, 0, stream>>>(rots, trans, intrins, post_rots,
                                               post_trans, counts, bins, ovf);
    gather_tiles<<<GBLOCKS, 1024, 0, stream>>>(x, counts, bins, out);
    overflow_splat<<<16, 256, 0, stream>>>(x, rots, trans, intrins, post_rots,
                                           post_trans, counts, ovf, out);
  } else {
    float* mats = (float*)d_ws;  // 4.6 KB
    hipMemsetAsync(d_out, 0, (size_t)out_size * sizeof(float), stream);
    prep_mats<<<1, 64, 0, stream>>>(rots, trans, intrins, post_rots, post_trans, mats);
    lss_splat_direct<<<(NPTS + 3) / 4, 256, 0, stream>>>(x, mats, out);
  }
}

// Round 9
// 73.968 us; speedup vs baseline: 1.7012x; 1.0262x over previous
//
#include <hip/hip_runtime.h>
#include <math.h>

namespace {

constexpr int B  = 8;
constexpr int N  = 6;
constexpr int D  = 41;
constexpr int FH = 8;    // 128/16
constexpr int FW = 22;   // 352/16
constexpr int C  = 64;
constexpr int NPTS = B * N * D * FH * FW;   // 346368 = 1353 * 256
constexpr int NX0 = 200, NX1 = 200, NX2 = 1;
constexpr int NVOX = NX0 * NX1;             // 40000 voxels per batch (gz==0)
constexpr int MAT_STRIDE = 24;
constexpr int VTILES = NVOX / 64;           // 625 tiles per batch
constexpr int NTILES = B * VTILES;          // 5000
constexpr int CAP    = 4096;                // bin capacity per tile (ints)
constexpr int GBLOCKS = 256;                // gather blocks: 1 per CU, co-resident

__device__ inline void inv3x3(const float a[9], float r[9]) {
  float c00 = a[4] * a[8] - a[5] * a[7];
  float c01 = a[5] * a[6] - a[3] * a[8];
  float c02 = a[3] * a[7] - a[4] * a[6];
  float det = a[0] * c00 + a[1] * c01 + a[2] * c02;
  float id  = 1.0f / det;
  r[0] = c00 * id;
  r[1] = (a[2] * a[7] - a[1] * a[8]) * id;
  r[2] = (a[1] * a[5] - a[2] * a[4]) * id;
  r[3] = c01 * id;
  r[4] = (a[0] * a[8] - a[2] * a[6]) * id;
  r[5] = (a[2] * a[3] - a[0] * a[5]) * id;
  r[6] = c02 * id;
  r[7] = (a[1] * a[6] - a[0] * a[7]) * id;
  r[8] = (a[0] * a[4] - a[1] * a[3]) * id;
}

__device__ inline void build_mats(int i,
                                  const float* __restrict__ rots,
                                  const float* __restrict__ trans,
                                  const float* __restrict__ intrins,
                                  const float* __restrict__ post_rots,
                                  const float* __restrict__ post_trans,
                                  float* __restrict__ o) {
#pragma clang fp contract(off)
  const float eps = 1e-6f;
  float m[9], inv_post[9], ki[9];

  for (int k = 0; k < 9; ++k) m[k] = post_rots[i * 9 + k];
  m[0] += eps; m[4] += eps; m[8] += eps;
  inv3x3(m, inv_post);

  for (int k = 0; k < 9; ++k) m[k] = intrins[i * 9 + k];
  m[0] += eps; m[4] += eps; m[8] += eps;
  inv3x3(m, ki);

  for (int k = 0; k < 9; ++k) o[k] = inv_post[k];
  for (int r = 0; r < 3; ++r)
    for (int c = 0; c < 3; ++c)
      o[9 + r * 3 + c] = rots[i * 9 + r * 3 + 0] * ki[0 * 3 + c]
                       + rots[i * 9 + r * 3 + 1] * ki[1 * 3 + c]
                       + rots[i * 9 + r * 3 + 2] * ki[2 * 3 + c];
  for (int k = 0; k < 3; ++k) o[18 + k] = trans[i * 3 + k];
  for (int k = 0; k < 3; ++k) o[21 + k] = post_trans[i * 3 + k];
}

__device__ inline int point_voxel(int wid, const float* __restrict__ mats) {
#pragma clang fp contract(off)
  int t  = wid;
  int w  = t % FW;  t /= FW;
  int h  = t % FH;  t /= FH;
  int dd = t % D;   t /= D;
  int n  = t % N;
  int b  = t / N;

  const float* M = mats + (b * N + n) * MAT_STRIDE;

  float u   = (float)w * (351.0f / 21.0f);
  float v   = (float)h * (127.0f / 7.0f);
  float dep = 4.0f + (float)dd;

  float p0 = u - M[21], p1 = v - M[22], p2 = dep - M[23];

  float q0 = M[0] * p0 + M[1] * p1 + M[2] * p2;
  float q1 = M[3] * p0 + M[4] * p1 + M[5] * p2;
  float q2 = M[6] * p0 + M[7] * p1 + M[8] * p2;

  float sd;
  if (fabsf(q2) < 1e-6f) {
    float t2 = q2 + 1e-6f;
    float s  = (t2 > 0.0f) ? 1.0f : ((t2 < 0.0f) ? -1.0f : 0.0f);
    sd = 1e-6f * s;
  } else {
    sd = q2;
  }
  float r0 = q0 * sd, r1 = q1 * sd, r2 = sd;

  float g0 = (M[9]  * r0 + M[10] * r1 + M[11] * r2) + M[18];
  float g1 = (M[12] * r0 + M[13] * r1 + M[14] * r2) + M[19];
  float g2 = (M[15] * r0 + M[16] * r1 + M[17] * r2) + M[20];

  float gnx = (g0 + 50.0f) / 0.5f;
  float gny = (g1 + 50.0f) / 0.5f;
  float gnz = (g2 + 10.0f) / 20.0f;
  int gx = (int)gnx;
  int gy = (int)gny;
  int gz = (int)gnz;

  if (gx < 0 || gx >= NX0 || gy < 0 || gy >= NX1 || gz < 0 || gz >= NX2)
    return -1;
  return b * NVOX + gx * NX1 + gy;   // global voxel id (gz == 0)
}

// Pass 0: clear per-tile counts + overflow counter (5001 ints).
__global__ __launch_bounds__(256) void clear_counts(int* __restrict__ counts) {
  int i = blockIdx.x * 256 + threadIdx.x;
  if (i <= NTILES) counts[i] = 0;
}

// Pass 1: bin kept points by output tile. Entry packs pid (19b) | v_in_tile (6b).
__global__ __launch_bounds__(256) void bin_points(const float* __restrict__ rots,
                                                  const float* __restrict__ trans,
                                                  const float* __restrict__ intrins,
                                                  const float* __restrict__ post_rots,
                                                  const float* __restrict__ post_trans,
                                                  int* __restrict__ counts,
                                                  int* __restrict__ bins,
                                                  int* __restrict__ ovf) {
  __shared__ float smats[B * N * MAT_STRIDE];
  int t = threadIdx.x;
  if (t < B * N)
    build_mats(t, rots, trans, intrins, post_rots, post_trans, smats + t * MAT_STRIDE);
  __syncthreads();

  int pid = blockIdx.x * 256 + t;           // NPTS is a multiple of 256
  int v = point_voxel(pid, smats);
  if (v < 0) return;

  int bt  = v >> 6;                         // tile id (NVOX % 64 == 0)
  int vin = v & 63;
  int idx = atomicAdd(&counts[bt], 1);
  if (idx < CAP) {
    bins[(size_t)bt * CAP + idx] = pid | (vin << 19);
  } else {
    int o = atomicAdd(&counts[NTILES], 1);  // overflow counter
    if (o < NPTS) ovf[o] = pid;
  }
}

// Pass 2: persistent gather, 1 block/CU. __launch_bounds__(1024, 4) -> 4 waves
// per SIMD -> 128-VGPR cap, so the 16 independent x-loads per round actually
// stay in flight (round 8's 64-VGPR cap serialized them; VGPR_Count was 32).
// Empty tiles stream zeros inside the persistent loop (no block churn); counts
// for the next tile are prefetched one iteration ahead.
__global__ __launch_bounds__(1024, 4) void gather_tiles(const float* __restrict__ x,
                                                        const int* __restrict__ counts,
                                                        const int* __restrict__ bins,
                                                        float* __restrict__ out) {
  __shared__ float tile[64][65];
  int t    = threadIdx.x;
  int lane = t & 63;
  int wv   = t >> 6;                        // wave id, 0..15
  int v4   = (t & 15) * 4;                  // voxel group for output writes
  int c    = t >> 4;                        // channel 0..63

  int bt  = blockIdx.x;
  int cnt = (bt < NTILES) ? counts[bt] : 0;

  for (; bt < NTILES; bt += GBLOCKS) {
    int nbt  = bt + GBLOCKS;
    int ncnt = (nbt < NTILES) ? counts[nbt] : 0;   // prefetch next tile's count

    int b  = bt / VTILES;
    int v0 = (bt % VTILES) * 64;

    if (cnt == 0) {
      *(float4*)(out + ((size_t)(b * C + c)) * NVOX + v0 + v4) =
          make_float4(0.f, 0.f, 0.f, 0.f);
      cnt = ncnt;
      continue;                             // block-uniform branch
    }

    __syncthreads();                        // LDS reuse guard (prev tile's reads done)
    for (int i = t; i < 64 * 65; i += 1024) ((float*)tile)[i] = 0.f;
    __syncthreads();

    int n = cnt < CAP ? cnt : CAP;
    const int* tb = bins + (size_t)bt * CAP;

    for (int j0 = wv * 16; j0 < n; j0 += 16 * 16) {
      int e = -1;
      if (lane < 16 && j0 + lane < n) e = tb[j0 + lane];

      float vals[16];
      int   vins[16];
      bool  ok[16];
#pragma unroll
      for (int k = 0; k < 16; ++k) {
        int ek  = __shfl(e, k);
        ok[k]   = ek >= 0;
        vins[k] = (ek >> 19) & 63;
        int pid = ek & 0x7FFFF;
        vals[k] = ok[k] ? x[(size_t)pid * C + lane] : 0.f;   // 16 loads in flight
      }
#pragma unroll
      for (int k = 0; k < 16; ++k)
        if (ok[k]) atomicAdd(&tile[vins[k]][lane], vals[k]);
    }
    __syncthreads();

    float4 vv;
    vv.x = tile[v4 + 0][c];
    vv.y = tile[v4 + 1][c];
    vv.z = tile[v4 + 2][c];
    vv.w = tile[v4 + 3][c];
    *(float4*)(out + ((size_t)(b * C + c)) * NVOX + v0 + v4) = vv;

    cnt = ncnt;
  }
}

// Pass 3: drain overflow list (normally empty) with direct atomics onto out.
// Must remain a separate dispatch: these atomics race with gather's plain
// stores if merged into the same kernel.
__global__ __launch_bounds__(256) void overflow_splat(const float* __restrict__ x,
                                                      const float* __restrict__ rots,
                                                      const float* __restrict__ trans,
                                                      const float* __restrict__ intrins,
                                                      const float* __restrict__ post_rots,
                                                      const float* __restrict__ post_trans,
                                                      const int* __restrict__ counts,
                                                      const int* __restrict__ ovf,
                                                      float* __restrict__ out) {
  int n = counts[NTILES];
  if (n <= 0) return;
  if (n > NPTS) n = NPTS;

  __shared__ float smats[B * N * MAT_STRIDE];
  int t = threadIdx.x;
  if (t < B * N)
    build_mats(t, rots, trans, intrins, post_rots, post_trans, smats + t * MAT_STRIDE);
  __syncthreads();

  int lane = t & 63;
  int wid  = (blockIdx.x * 256 + t) >> 6;
  int nw   = (gridDim.x * 256) >> 6;
  for (int i = wid; i < n; i += nw) {
    int pid = ovf[i];
    int v = point_voxel(pid, smats);
    if (v < 0) continue;
    int b   = v / NVOX;
    int loc = v % NVOX;
    atomicAdd(out + ((size_t)(b * C + lane)) * NVOX + loc, x[(size_t)pid * C + lane]);
  }
}

// ---- minimal-ws fallback: direct atomics into out ----
__global__ void prep_mats(const float* __restrict__ rots,
                          const float* __restrict__ trans,
                          const float* __restrict__ intrins,
                          const float* __restrict__ post_rots,
                          const float* __restrict__ post_trans,
                          float* __restrict__ mats) {
  int i = blockIdx.x * blockDim.x + threadIdx.x;
  if (i >= B * N) return;
  build_mats(i, rots, trans, intrins, post_rots, post_trans, mats + i * MAT_STRIDE);
}

__global__ __launch_bounds__(256) void lss_splat_direct(const float* __restrict__ x,
                                                        const float* __restrict__ mats,
                                                        float* __restrict__ out) {
  int wid  = blockIdx.x * 4 + (threadIdx.x >> 6);
  if (wid >= NPTS) return;
  int lane = threadIdx.x & 63;
  int voxel = point_voxel(wid, mats);
  if (voxel < 0) return;
  int b = voxel / NVOX;
  int v = voxel % NVOX;
  float val = x[(size_t)wid * C + lane];
  size_t oidx = ((size_t)(b * C + lane)) * NVOX + v;
  atomicAdd(out + oidx, val);
}

}  // namespace

extern "C" void kernel_launch(void* const* d_in, const int* in_sizes, int n_in,
                              void* d_out, int out_size, void* d_ws, size_t ws_size,
                              hipStream_t stream) {
  const float* x          = (const float*)d_in[0];
  const float* rots       = (const float*)d_in[1];
  const float* trans      = (const float*)d_in[2];
  const float* intrins    = (const float*)d_in[3];
  const float* post_rots  = (const float*)d_in[4];
  const float* post_trans = (const float*)d_in[5];
  float* out = (float*)d_out;

  // ws layout: counts[NTILES+1] | bins[NTILES*CAP] | ovf[NPTS]
  const size_t bins_off = (((size_t)(NTILES + 1) * sizeof(int)) + 255) & ~(size_t)255;
  const size_t ovf_off  = bins_off + (size_t)NTILES * CAP * sizeof(int);
  const size_t need     = ovf_off + (size_t)NPTS * sizeof(int);

  if (ws_size >= need) {
    int* counts = (int*)d_ws;
    int* bins   = (int*)((char*)d_ws + bins_off);
    int* ovf    = (int*)((char*)d_ws + ovf_off);

    clear_counts<<<(NTILES + 1 + 255) / 256, 256, 0, stream>>>(counts);
    bin_points<<<NPTS / 256, 256, 0, stream>>>(rots, trans, intrins, post_rots,
                                               post_trans, counts, bins, ovf);
    gather_tiles<<<GBLOCKS, 1024, 0, stream>>>(x, counts, bins, out);
    overflow_splat<<<16, 256, 0, stream>>>(x, rots, trans, intrins, post_rots,
                                           post_trans, counts, ovf, out);
  } else {
    float* mats = (float*)d_ws;  // 4.6 KB
    hipMemsetAsync(d_out, 0, (size_t)out_size * sizeof(float), stream);
    prep_mats<<<1, 64, 0, stream>>>(rots, trans, intrins, post_rots, post_trans, mats);
    lss_splat_direct<<<(NPTS + 3) / 4, 256, 0, stream>>>(x, mats, out);
  }
}